// Round 6
// baseline (561.248 us; speedup 1.0000x reference)
//
#include <hip/hip_runtime.h>

// ---------------------------------------------------------------------------
// CellVGAE GCN encoder: x -> GCN(512,128)+ReLU -> GCN(128,128)+ReLU
//                         -> {GCN(128,64) mean, GCN(128,64) log_std}
// Round 6: barrier-free direct-fragment MFMA GEMM (no LDS). Round-5 profile
// showed the 2-barrier LDS K-loop latency-bound (Mfma 11%, VALU 8%, occ 21%);
// MFMA fragments are k-contiguous so they load straight from global.
// Propagates now emit split bf16 hi/lo (same bytes) so K=128 GEMMs skip the
// in-register split entirely.
// ---------------------------------------------------------------------------

using u16 = unsigned short;
typedef __attribute__((ext_vector_type(8))) short short8;
typedef __attribute__((ext_vector_type(4))) float f32x4;

__device__ __forceinline__ void split_bf16(float f, u16& hi, u16& lo) {
    unsigned b = __float_as_uint(f);
    hi = (u16)(b >> 16);
    float rem = f - __uint_as_float(b & 0xFFFF0000u);
    lo = (u16)(__float_as_uint(rem) >> 16);
}

// Block-wide mode detect: 1 = int64 edge_index, 0 = int32.
__device__ __forceinline__ int block_mode(const int* __restrict__ ew, int* sflag) {
    if (threadIdx.x == 0) *sflag = 0;
    __syncthreads();
    if (ew[2 * (int)threadIdx.x + 1] != 0) atomicOr(sflag, 1);
    __syncthreads();
    return *sflag ? 0 : 1;
}

// ---- degree count (mode detect inlined) -----------------------------------
__global__ void deg_kernel(const int* __restrict__ ew, int* __restrict__ deg, int E) {
    __shared__ int sflag;
    int mode = block_mode(ew, &sflag);
    int e = blockIdx.x * blockDim.x + threadIdx.x;
    if (e >= E) return;
    int d = mode ? ew[2 * E + 2 * e] : ew[E + e];
    atomicAdd(&deg[d], 1);
}

// ---- exclusive scan over deg -> rowptr, fused dis = rsqrt(deg+1) ----------
__global__ void scan_block_kernel(const int* __restrict__ deg, int* __restrict__ rowptr,
                                  int* __restrict__ aux, float* __restrict__ dis, int N) {
    __shared__ int s[256];
    int i = blockIdx.x * 256 + threadIdx.x;
    int v = (i < N) ? deg[i] : 0;
    if (i < N) dis[i] = rsqrtf((float)v + 1.0f);
    s[threadIdx.x] = v;
    __syncthreads();
    for (int off = 1; off < 256; off <<= 1) {
        int t = (threadIdx.x >= off) ? s[threadIdx.x - off] : 0;
        __syncthreads();
        s[threadIdx.x] += t;
        __syncthreads();
    }
    if (i < N) rowptr[i] = s[threadIdx.x] - v;
    if (threadIdx.x == 255) aux[blockIdx.x] = s[255];
}

__global__ void scan_aux_kernel(int* __restrict__ aux, int nb) {
    __shared__ int s[256];
    int i = threadIdx.x;
    int v = (i < nb) ? aux[i] : 0;
    s[i] = v;
    __syncthreads();
    for (int off = 1; off < 256; off <<= 1) {
        int t = (i >= off) ? s[i - off] : 0;
        __syncthreads();
        s[i] += t;
        __syncthreads();
    }
    if (i < nb) aux[i] = s[i] - v;
}

__global__ void add_offsets_kernel(int* __restrict__ rowptr, const int* __restrict__ aux,
                                   int N, int E) {
    int i = blockIdx.x * 256 + threadIdx.x;
    if (i < N) rowptr[i] += aux[i >> 8];
    if (i == 0) rowptr[N] = E;
}

// ---- CSR fill (mode detect inlined) ---------------------------------------
__global__ void fill_csr_kernel(const int* __restrict__ ew,
                                const int* __restrict__ rowptr, int* __restrict__ cursor,
                                int* __restrict__ csr_src, int E) {
    __shared__ int sflag;
    int mode = block_mode(ew, &sflag);
    int e = blockIdx.x * blockDim.x + threadIdx.x;
    if (e >= E) return;
    int s = mode ? ew[2 * e] : ew[e];
    int d = mode ? ew[2 * E + 2 * e] : ew[E + e];
    int pos = rowptr[d] + atomicAdd(&cursor[d], 1);
    csr_src[pos] = s;
}

// ---- all weight transposed-splits in one kernel ---------------------------
__global__ void conv_all_kernel(const float* __restrict__ W1, const float* __restrict__ W2,
                                const float* __restrict__ Wm, const float* __restrict__ Ws,
                                u16* __restrict__ W1t_hi, u16* __restrict__ W1t_lo,
                                u16* __restrict__ W2t_hi, u16* __restrict__ W2t_lo,
                                u16* __restrict__ Wct_hi, u16* __restrict__ Wct_lo) {
    int idx = blockIdx.x * 256 + threadIdx.x;
    u16 h, l;
    if (idx < 65536) {                 // W1: 512x128 -> [128][512]
        int k = idx >> 7, n = idx & 127;
        split_bf16(W1[idx], h, l);
        W1t_hi[n * 512 + k] = h;
        W1t_lo[n * 512 + k] = l;
    } else if (idx < 81920) {          // W2: 128x128 -> [128][128]
        int t = idx - 65536;
        int k = t >> 7, n = t & 127;
        split_bf16(W2[t], h, l);
        W2t_hi[n * 128 + k] = h;
        W2t_lo[n * 128 + k] = l;
    } else if (idx < 98304) {          // [Wm|Ws]: 128x128 -> [128][128]
        int t = idx - 81920;
        int k = t >> 7, j = t & 127;
        float f = (j < 64) ? Wm[k * 64 + j] : Ws[k * 64 + (j - 64)];
        split_bf16(f, h, l);
        Wct_hi[j * 128 + k] = h;
        Wct_lo[j * 128 + k] = l;
    }
}

// ---- barrier-free direct-fragment MFMA GEMM -------------------------------
// C[N x 128] = A[N x K] @ B[K x 128]. B pre-split+transposed (u16 [128][K]).
// SPLIT=false: A is f32 [N][K], split to hi/lo in-register.
// SPLIT=true : A is pre-split u16 Ahi/Alo [N][K].
// Block = 64 rows x 128 cols, 4 waves of 32x64 (2x4 MFMA tiles). Fragments
// are k-contiguous => loaded directly from global; no LDS, no barriers.
template <int K, bool SPLIT>
__global__ __launch_bounds__(256) void gemm_direct(
    const float* __restrict__ A,
    const u16* __restrict__ Ahi, const u16* __restrict__ Alo,
    const u16* __restrict__ Bh, const u16* __restrict__ Bl,
    float* __restrict__ C, int N) {
    const int tid = threadIdx.x;
    const int w = tid >> 6, lane = tid & 63;
    const int row0 = blockIdx.x * 64;
    const int R = (w >> 1) * 32, Cc = (w & 1) * 64;
    const int m16 = lane & 15, quad = lane >> 4, kq = quad * 8;

    int r0 = row0 + R + m16;
    int r1 = r0 + 16;
    if (r0 > N - 1) r0 = N - 1;   // clamp: no OOB reads; stores guarded below
    if (r1 > N - 1) r1 = N - 1;

    const float* a0;
    const float* a1;
    const u16 *ah0, *ah1, *al0, *al1;
    if constexpr (SPLIT) {
        ah0 = Ahi + (size_t)r0 * K + kq;
        ah1 = Ahi + (size_t)r1 * K + kq;
        al0 = Alo + (size_t)r0 * K + kq;
        al1 = Alo + (size_t)r1 * K + kq;
    } else {
        a0 = A + (size_t)r0 * K + kq;
        a1 = A + (size_t)r1 * K + kq;
    }
    const u16* bhp[4];
    const u16* blp[4];
#pragma unroll
    for (int j = 0; j < 4; ++j) {
        int n = Cc + j * 16 + m16;
        bhp[j] = Bh + (size_t)n * K + kq;
        blp[j] = Bl + (size_t)n * K + kq;
    }

    f32x4 acc[2][4];
#pragma unroll
    for (int i = 0; i < 2; ++i)
#pragma unroll
        for (int j = 0; j < 4; ++j) acc[i][j] = (f32x4)0.f;

    // ---- register pipeline: current + next ----
    float curA[2][8];
    short8 curAh[2], curAl[2];
    short8 curBh[4], curBl[4];

    // prime step 0
    if constexpr (SPLIT) {
        curAh[0] = *(const short8*)&ah0[0];
        curAh[1] = *(const short8*)&ah1[0];
        curAl[0] = *(const short8*)&al0[0];
        curAl[1] = *(const short8*)&al1[0];
    } else {
        f32x4 v00 = *(const f32x4*)&a0[0], v01 = *(const f32x4*)&a0[4];
        f32x4 v10 = *(const f32x4*)&a1[0], v11 = *(const f32x4*)&a1[4];
#pragma unroll
        for (int q = 0; q < 4; ++q) {
            curA[0][q] = v00[q]; curA[0][4 + q] = v01[q];
            curA[1][q] = v10[q]; curA[1][4 + q] = v11[q];
        }
    }
#pragma unroll
    for (int j = 0; j < 4; ++j) {
        curBh[j] = *(const short8*)&bhp[j][0];
        curBl[j] = *(const short8*)&blp[j][0];
    }

    const int NSTEP = K / 32;
#pragma unroll
    for (int ks = 0; ks < NSTEP; ++ks) {
        float nxtA[2][8];
        short8 nxtAh[2], nxtAl[2], nxtBh[4], nxtBl[4];
        const bool more = (ks + 1 < NSTEP);
        if (more) {
            const int kb = (ks + 1) * 32;
            if constexpr (SPLIT) {
                nxtAh[0] = *(const short8*)&ah0[kb];
                nxtAh[1] = *(const short8*)&ah1[kb];
                nxtAl[0] = *(const short8*)&al0[kb];
                nxtAl[1] = *(const short8*)&al1[kb];
            } else {
                f32x4 v00 = *(const f32x4*)&a0[kb], v01 = *(const f32x4*)&a0[kb + 4];
                f32x4 v10 = *(const f32x4*)&a1[kb], v11 = *(const f32x4*)&a1[kb + 4];
#pragma unroll
                for (int q = 0; q < 4; ++q) {
                    nxtA[0][q] = v00[q]; nxtA[0][4 + q] = v01[q];
                    nxtA[1][q] = v10[q]; nxtA[1][4 + q] = v11[q];
                }
            }
#pragma unroll
            for (int j = 0; j < 4; ++j) {
                nxtBh[j] = *(const short8*)&bhp[j][kb];
                nxtBl[j] = *(const short8*)&blp[j][kb];
            }
        }

        // A hi/lo fragments for this step
        short8 ah[2], al[2];
        if constexpr (SPLIT) {
#pragma unroll
            for (int i = 0; i < 2; ++i) { ah[i] = curAh[i]; al[i] = curAl[i]; }
        } else {
#pragma unroll
            for (int i = 0; i < 2; ++i)
#pragma unroll
                for (int q = 0; q < 8; ++q) {
                    u16 h, l;
                    split_bf16(curA[i][q], h, l);
                    ah[i][q] = (short)h;
                    al[i][q] = (short)l;
                }
        }

#pragma unroll
        for (int i = 0; i < 2; ++i)
#pragma unroll
            for (int j = 0; j < 4; ++j) {
                acc[i][j] = __builtin_amdgcn_mfma_f32_16x16x32_bf16(
                    ah[i], curBh[j], acc[i][j], 0, 0, 0);
                acc[i][j] = __builtin_amdgcn_mfma_f32_16x16x32_bf16(
                    ah[i], curBl[j], acc[i][j], 0, 0, 0);
                acc[i][j] = __builtin_amdgcn_mfma_f32_16x16x32_bf16(
                    al[i], curBh[j], acc[i][j], 0, 0, 0);
            }

        if (more) {
            if constexpr (SPLIT) {
#pragma unroll
                for (int i = 0; i < 2; ++i) { curAh[i] = nxtAh[i]; curAl[i] = nxtAl[i]; }
            } else {
#pragma unroll
                for (int i = 0; i < 2; ++i)
#pragma unroll
                    for (int q = 0; q < 8; ++q) curA[i][q] = nxtA[i][q];
            }
#pragma unroll
            for (int j = 0; j < 4; ++j) { curBh[j] = nxtBh[j]; curBl[j] = nxtBl[j]; }
        }
    }

    // epilogue: C/D layout col=lane&15, row=quad*4+reg
#pragma unroll
    for (int i = 0; i < 2; ++i) {
#pragma unroll
        for (int r = 0; r < 4; ++r) {
            int gr = row0 + R + i * 16 + quad * 4 + r;
            if (gr < N) {
#pragma unroll
                for (int j = 0; j < 4; ++j)
                    C[(size_t)gr * 128 + Cc + j * 16 + m16] = acc[i][j][r];
            }
        }
    }
}

// ---- propagate: gather + normalize; OUTPUT = split bf16 hi/lo -------------
__global__ __launch_bounds__(256) void propagate_kernel(
    const float* __restrict__ h, const int* __restrict__ rowptr,
    const int* __restrict__ csr_src, const float* __restrict__ dis,
    const float* __restrict__ bias, u16* __restrict__ out_hi,
    u16* __restrict__ out_lo, int N) {
    int wave = (blockIdx.x * 256 + threadIdx.x) >> 6;
    int lane = threadIdx.x & 63;
    if (wave >= N) return;
    int v = wave;
    int f = lane * 2;
    float dv = dis[v];
    float ax = 0.f, ay = 0.f;
    int beg = rowptr[v], end = rowptr[v + 1];
    int i = beg;
    for (; i + 8 <= end; i += 8) {
        int s[8];
        float ww[8];
        float2 g[8];
#pragma unroll
        for (int u = 0; u < 8; ++u) s[u] = csr_src[i + u];
#pragma unroll
        for (int u = 0; u < 8; ++u) ww[u] = dis[s[u]];
#pragma unroll
        for (int u = 0; u < 8; ++u) g[u] = *(const float2*)&h[(size_t)s[u] * 128 + f];
#pragma unroll
        for (int u = 0; u < 8; ++u) {
            float t = ww[u] * dv;
            ax += t * g[u].x;
            ay += t * g[u].y;
        }
    }
    if (i + 4 <= end) {
        int s[4];
        float ww[4];
        float2 g[4];
#pragma unroll
        for (int u = 0; u < 4; ++u) s[u] = csr_src[i + u];
#pragma unroll
        for (int u = 0; u < 4; ++u) ww[u] = dis[s[u]];
#pragma unroll
        for (int u = 0; u < 4; ++u) g[u] = *(const float2*)&h[(size_t)s[u] * 128 + f];
#pragma unroll
        for (int u = 0; u < 4; ++u) {
            float t = ww[u] * dv;
            ax += t * g[u].x;
            ay += t * g[u].y;
        }
        i += 4;
    }
    for (; i < end; ++i) {
        int s = csr_src[i];
        float ws = dis[s] * dv;
        float2 g = *(const float2*)&h[(size_t)s * 128 + f];
        ax += ws * g.x;
        ay += ws * g.y;
    }
    float2 hv = *(const float2*)&h[(size_t)v * 128 + f];
    ax += dv * dv * hv.x;
    ay += dv * dv * hv.y;
    ax += bias[f];
    ay += bias[f + 1];
    ax = fmaxf(ax, 0.f);   // both prop layers have ReLU
    ay = fmaxf(ay, 0.f);
    u16 hx, lx, hy, ly;
    split_bf16(ax, hx, lx);
    split_bf16(ay, hy, ly);
    *(ushort2*)&out_hi[(size_t)v * 128 + f] = make_ushort2(hx, hy);
    *(ushort2*)&out_lo[(size_t)v * 128 + f] = make_ushort2(lx, ly);
}

// ---- final propagate: split into z_mean / z_log_std (f32 out) -------------
__global__ __launch_bounds__(256) void propagate_final_kernel(
    const float* __restrict__ h, const int* __restrict__ rowptr,
    const int* __restrict__ csr_src, const float* __restrict__ dis,
    const float* __restrict__ bm, const float* __restrict__ bs,
    float* __restrict__ out, int N) {
    int wave = (blockIdx.x * 256 + threadIdx.x) >> 6;
    int lane = threadIdx.x & 63;
    if (wave >= N) return;
    int v = wave;
    int f = lane * 2;
    float dv = dis[v];
    float ax = 0.f, ay = 0.f;
    int beg = rowptr[v], end = rowptr[v + 1];
    int i = beg;
    for (; i + 8 <= end; i += 8) {
        int s[8];
        float ww[8];
        float2 g[8];
#pragma unroll
        for (int u = 0; u < 8; ++u) s[u] = csr_src[i + u];
#pragma unroll
        for (int u = 0; u < 8; ++u) ww[u] = dis[s[u]];
#pragma unroll
        for (int u = 0; u < 8; ++u) g[u] = *(const float2*)&h[(size_t)s[u] * 128 + f];
#pragma unroll
        for (int u = 0; u < 8; ++u) {
            float t = ww[u] * dv;
            ax += t * g[u].x;
            ay += t * g[u].y;
        }
    }
    if (i + 4 <= end) {
        int s[4];
        float ww[4];
        float2 g[4];
#pragma unroll
        for (int u = 0; u < 4; ++u) s[u] = csr_src[i + u];
#pragma unroll
        for (int u = 0; u < 4; ++u) ww[u] = dis[s[u]];
#pragma unroll
        for (int u = 0; u < 4; ++u) g[u] = *(const float2*)&h[(size_t)s[u] * 128 + f];
#pragma unroll
        for (int u = 0; u < 4; ++u) {
            float t = ww[u] * dv;
            ax += t * g[u].x;
            ay += t * g[u].y;
        }
        i += 4;
    }
    for (; i < end; ++i) {
        int s = csr_src[i];
        float ws = dis[s] * dv;
        float2 g = *(const float2*)&h[(size_t)s * 128 + f];
        ax += ws * g.x;
        ay += ws * g.y;
    }
    float2 hv = *(const float2*)&h[(size_t)v * 128 + f];
    ax += dv * dv * hv.x;
    ay += dv * dv * hv.y;
    if (f < 64) {
        *(float2*)&out[(size_t)v * 64 + f] = make_float2(ax + bm[f], ay + bm[f + 1]);
    } else {
        int g = f - 64;
        *(float2*)&out[(size_t)N * 64 + (size_t)v * 64 + g] =
            make_float2(ax + bs[g], ay + bs[g + 1]);
    }
}

extern "C" void kernel_launch(void* const* d_in, const int* in_sizes, int n_in,
                              void* d_out, int out_size, void* d_ws, size_t ws_size,
                              hipStream_t stream) {
    const float* x  = (const float*)d_in[0];
    const int*   ew = (const int*)d_in[1];
    const float* W1 = (const float*)d_in[2];
    const float* b1 = (const float*)d_in[3];
    const float* W2 = (const float*)d_in[4];
    const float* b2 = (const float*)d_in[5];
    const float* Wm = (const float*)d_in[6];
    const float* bm = (const float*)d_in[7];
    const float* Ws = (const float*)d_in[8];
    const float* bs = (const float*)d_in[9];
    float* out = (float*)d_out;

    const int IN = 512, H = 128;
    const int N = in_sizes[0] / IN;     // 50000
    const int E = in_sizes[1] / 2;      // 800000

    // ---- workspace: ~55.6 MB total (< proven-safe 58.47 MB) ----------------
    char* base = (char*)d_ws;
    size_t off = 0;
    auto alloc = [&](size_t bytes) -> char* {
        char* p = base + off;
        off = (off + bytes + 255) & ~(size_t)255;
        return p;
    };
    char*  degcur  = (char*) alloc(400384);             // deg + cursor (zeroed)
    float* dis     = (float*)alloc((size_t)N * 4);
    int*   rowptr  = (int*)  alloc((size_t)(N + 1) * 4);
    int*   aux     = (int*)  alloc(256 * 4);
    int*   csr_src = (int*)  alloc((size_t)E * 4);
    u16*   W1t_hi  = (u16*)  alloc((size_t)IN * H * 2);
    u16*   W1t_lo  = (u16*)  alloc((size_t)IN * H * 2);
    u16*   W2t_hi  = (u16*)  alloc((size_t)H * H * 2);
    u16*   W2t_lo  = (u16*)  alloc((size_t)H * H * 2);
    u16*   Wct_hi  = (u16*)  alloc((size_t)H * H * 2);
    u16*   Wct_lo  = (u16*)  alloc((size_t)H * H * 2);
    float* hA      = (float*)alloc((size_t)N * H * 4);  // GEMM outputs (f32)
    u16*   hBhi    = (u16*)  alloc((size_t)N * H * 2);  // propagate out hi
    u16*   hBlo    = (u16*)  alloc((size_t)N * H * 2);  // propagate out lo
    (void)ws_size; (void)n_in; (void)out_size;

    int* deg    = (int*)degcur;
    int* cursor = (int*)(degcur + 200192);

    hipMemsetAsync(degcur, 0, 400384, stream);

    const int eblocks = (E + 255) / 256;
    const int nblocks = (N + 255) / 256;

    conv_all_kernel<<<(98304 + 255) / 256, 256, 0, stream>>>(
        W1, W2, Wm, Ws, W1t_hi, W1t_lo, W2t_hi, W2t_lo, Wct_hi, Wct_lo);
    deg_kernel<<<eblocks, 256, 0, stream>>>(ew, deg, E);
    scan_block_kernel<<<nblocks, 256, 0, stream>>>(deg, rowptr, aux, dis, N);
    scan_aux_kernel<<<1, 256, 0, stream>>>(aux, nblocks);
    add_offsets_kernel<<<nblocks, 256, 0, stream>>>(rowptr, aux, N, E);
    fill_csr_kernel<<<eblocks, 256, 0, stream>>>(ew, rowptr, cursor, csr_src, E);

    const int gblocks = (N + 63) / 64;   // 782
    const int pblocks = (N * 64 + 255) / 256;

    gemm_direct<512, false><<<gblocks, 256, 0, stream>>>(
        x, nullptr, nullptr, W1t_hi, W1t_lo, hA, N);
    propagate_kernel<<<pblocks, 256, 0, stream>>>(hA, rowptr, csr_src, dis,
                                                  b1, hBhi, hBlo, N);
    gemm_direct<128, true><<<gblocks, 256, 0, stream>>>(
        nullptr, hBhi, hBlo, W2t_hi, W2t_lo, hA, N);
    propagate_kernel<<<pblocks, 256, 0, stream>>>(hA, rowptr, csr_src, dis,
                                                  b2, hBhi, hBlo, N);
    gemm_direct<128, true><<<gblocks, 256, 0, stream>>>(
        nullptr, hBhi, hBlo, Wct_hi, Wct_lo, hA, N);
    propagate_final_kernel<<<pblocks, 256, 0, stream>>>(hA, rowptr, csr_src, dis,
                                                        bm, bs, out, N);
}

// Round 7
// 515.039 us; speedup vs baseline: 1.0897x; 1.0897x over previous
//
#include <hip/hip_runtime.h>

// ---------------------------------------------------------------------------
// CellVGAE GCN encoder: x -> GCN(512,128)+ReLU -> GCN(128,128)+ReLU
//                         -> {GCN(128,64) mean, GCN(128,64) log_std}
// Round 7: back to LDS-staged MFMA GEMM (round-6 direct loads were address-
// divergent -> VMEM-bound). Block tile 32x128 (was 64x128) => 1563 blocks
// ~ 6 blocks/CU (round-5 was grid-limited at 3). Propagates emit split bf16
// so K=128 GEMMs read pre-split A. conv+deg merged into one kernel.
// ---------------------------------------------------------------------------

using u16 = unsigned short;
typedef __attribute__((ext_vector_type(8))) short short8;
typedef __attribute__((ext_vector_type(4))) float f32x4;

__device__ __forceinline__ void split_bf16(float f, u16& hi, u16& lo) {
    unsigned b = __float_as_uint(f);
    hi = (u16)(b >> 16);
    float rem = f - __uint_as_float(b & 0xFFFF0000u);
    lo = (u16)(__float_as_uint(rem) >> 16);
}

// Block-wide mode detect: 1 = int64 edge_index, 0 = int32.
__device__ __forceinline__ int block_mode(const int* __restrict__ ew, int* sflag) {
    if (threadIdx.x == 0) *sflag = 0;
    __syncthreads();
    if (ew[2 * (int)threadIdx.x + 1] != 0) atomicOr(sflag, 1);
    __syncthreads();
    return *sflag ? 0 : 1;
}

// ---- merged: weight transposed-splits (blocks 0..383) + degree count ------
#define CONVB 384
__global__ void conv_deg_kernel(const float* __restrict__ W1, const float* __restrict__ W2,
                                const float* __restrict__ Wm, const float* __restrict__ Ws,
                                u16* __restrict__ W1t_hi, u16* __restrict__ W1t_lo,
                                u16* __restrict__ W2t_hi, u16* __restrict__ W2t_lo,
                                u16* __restrict__ Wct_hi, u16* __restrict__ Wct_lo,
                                const int* __restrict__ ew, int* __restrict__ deg, int E) {
    if (blockIdx.x < CONVB) {
        int idx = blockIdx.x * 256 + threadIdx.x;
        u16 h, l;
        if (idx < 65536) {                 // W1: 512x128 -> [128][512]
            int k = idx >> 7, n = idx & 127;
            split_bf16(W1[idx], h, l);
            W1t_hi[n * 512 + k] = h;
            W1t_lo[n * 512 + k] = l;
        } else if (idx < 81920) {          // W2: 128x128 -> [128][128]
            int t = idx - 65536;
            int k = t >> 7, n = t & 127;
            split_bf16(W2[t], h, l);
            W2t_hi[n * 128 + k] = h;
            W2t_lo[n * 128 + k] = l;
        } else if (idx < 98304) {          // [Wm|Ws]: 128x128 -> [128][128]
            int t = idx - 81920;
            int k = t >> 7, j = t & 127;
            float f = (j < 64) ? Wm[k * 64 + j] : Ws[k * 64 + (j - 64)];
            split_bf16(f, h, l);
            Wct_hi[j * 128 + k] = h;
            Wct_lo[j * 128 + k] = l;
        }
    } else {
        __shared__ int sflag;
        int mode = block_mode(ew, &sflag);
        int e = (blockIdx.x - CONVB) * 256 + threadIdx.x;
        if (e >= E) return;
        int d = mode ? ew[2 * E + 2 * e] : ew[E + e];
        atomicAdd(&deg[d], 1);
    }
}

// ---- exclusive scan over deg -> rowptr, fused dis = rsqrt(deg+1) ----------
__global__ void scan_block_kernel(const int* __restrict__ deg, int* __restrict__ rowptr,
                                  int* __restrict__ aux, float* __restrict__ dis, int N) {
    __shared__ int s[256];
    int i = blockIdx.x * 256 + threadIdx.x;
    int v = (i < N) ? deg[i] : 0;
    if (i < N) dis[i] = rsqrtf((float)v + 1.0f);
    s[threadIdx.x] = v;
    __syncthreads();
    for (int off = 1; off < 256; off <<= 1) {
        int t = (threadIdx.x >= off) ? s[threadIdx.x - off] : 0;
        __syncthreads();
        s[threadIdx.x] += t;
        __syncthreads();
    }
    if (i < N) rowptr[i] = s[threadIdx.x] - v;
    if (threadIdx.x == 255) aux[blockIdx.x] = s[255];
}

__global__ void scan_aux_kernel(int* __restrict__ aux, int nb) {
    __shared__ int s[256];
    int i = threadIdx.x;
    int v = (i < nb) ? aux[i] : 0;
    s[i] = v;
    __syncthreads();
    for (int off = 1; off < 256; off <<= 1) {
        int t = (i >= off) ? s[i - off] : 0;
        __syncthreads();
        s[i] += t;
        __syncthreads();
    }
    if (i < nb) aux[i] = s[i] - v;
}

__global__ void add_offsets_kernel(int* __restrict__ rowptr, const int* __restrict__ aux,
                                   int N, int E) {
    int i = blockIdx.x * 256 + threadIdx.x;
    if (i < N) rowptr[i] += aux[i >> 8];
    if (i == 0) rowptr[N] = E;
}

// ---- CSR fill (mode detect inlined) ---------------------------------------
__global__ void fill_csr_kernel(const int* __restrict__ ew,
                                const int* __restrict__ rowptr, int* __restrict__ cursor,
                                int* __restrict__ csr_src, int E) {
    __shared__ int sflag;
    int mode = block_mode(ew, &sflag);
    int e = blockIdx.x * blockDim.x + threadIdx.x;
    if (e >= E) return;
    int s = mode ? ew[2 * e] : ew[e];
    int d = mode ? ew[2 * E + 2 * e] : ew[E + e];
    int pos = rowptr[d] + atomicAdd(&cursor[d], 1);
    csr_src[pos] = s;
}

// ---- MFMA GEMM: C[N x 128] = A[N x K] @ B[K x 128] ------------------------
// Block tile 32 rows x 128 cols, 4 waves each 16x64 (1x4 MFMA tiles).
// Fragment-order LDS: tile t at t*520 u16, lane L's 16B frag at +L*8.
// SPLIT=false: A f32, split in-register. SPLIT=true: A pre-split hi/lo u16.
#define TILE_OFF(t) ((t) * 520)

template <int K, bool SPLIT>
__global__ __launch_bounds__(256) void gemm_tiled(
    const float* __restrict__ A,
    const u16* __restrict__ Ahi, const u16* __restrict__ Alo,
    const u16* __restrict__ Bh, const u16* __restrict__ Bl,
    float* __restrict__ C, int N) {
    __shared__ u16 AsH[2 * 520], AsL[2 * 520];   // 32 rows
    __shared__ u16 BsH[8 * 520], BsL[8 * 520];   // 128 cols

    const int tid = threadIdx.x;
    const int row0 = blockIdx.x * 32;

    // A staging: thread -> (row 0..31, k-quad of 4)
    const int arow = tid >> 3;                 // 0..31
    const int akq  = (tid & 7) * 4;            // 0,4,...,28
    const int a_dst = TILE_OFF(arow >> 4) + ((arow & 15) + 16 * (akq >> 3)) * 8 + (akq & 7);
    // B staging: thread -> (col 0..127, k-half)
    const int s_bc = tid >> 1;
    const int s_bk = (tid & 1) * 16;
    const int b_q0 = (tid & 1) * 2;
    const int b_dst0 = TILE_OFF(s_bc >> 4) + ((s_bc & 15) + 16 * (b_q0 + 0)) * 8;
    const int b_dst1 = TILE_OFF(s_bc >> 4) + ((s_bc & 15) + 16 * (b_q0 + 1)) * 8;

    // compute: wave w -> rows (w>>1)*16, cols (w&1)*64
    const int w = tid >> 6, lane = tid & 63;
    const int aw = w >> 1;
    const int Cc = (w & 1) * 64;
    const int btile = (w & 1) * 4;
    const int m16 = lane & 15, quad = lane >> 4;

    f32x4 acc[4];
#pragma unroll
    for (int j = 0; j < 4; ++j) acc[j] = (f32x4)0.f;

    int gr = row0 + arow;
    if (gr > N - 1) gr = N - 1;    // clamp reads; stores guarded
    const float* ap;
    const u16 *ahp, *alp;
    if constexpr (SPLIT) {
        ahp = Ahi + (size_t)gr * K + akq;
        alp = Alo + (size_t)gr * K + akq;
    } else {
        ap = A + (size_t)gr * K + akq;
    }
    const u16* bph = Bh + (size_t)s_bc * K + s_bk;
    const u16* bpl = Bl + (size_t)s_bc * K + s_bk;

    // register pipeline
    f32x4 avc;
    ushort4 ahc, alc;
    short8 bh0, bh1, bl0, bl1;
    if constexpr (SPLIT) {
        ahc = *(const ushort4*)&ahp[0];
        alc = *(const ushort4*)&alp[0];
    } else {
        avc = *(const f32x4*)&ap[0];
    }
    bh0 = *(const short8*)&bph[0];
    bh1 = *(const short8*)&bph[8];
    bl0 = *(const short8*)&bpl[0];
    bl1 = *(const short8*)&bpl[8];

    const int NSTEP = K / 32;
#pragma unroll
    for (int ks = 0; ks < NSTEP; ++ks) {
        // prepare A hi/lo 4-chunk
        ushort4 wh, wl;
        if constexpr (SPLIT) {
            wh = ahc; wl = alc;
        } else {
#pragma unroll
            for (int q = 0; q < 4; ++q) {
                u16 h, l;
                split_bf16(avc[q], h, l);
                (&wh.x)[q] = h;
                (&wl.x)[q] = l;
            }
        }
        __syncthreads();   // prior step's frag reads done
        *(ushort4*)&AsH[a_dst] = wh;
        *(ushort4*)&AsL[a_dst] = wl;
        *(short8*)&BsH[b_dst0] = bh0;
        *(short8*)&BsH[b_dst1] = bh1;
        *(short8*)&BsL[b_dst0] = bl0;
        *(short8*)&BsL[b_dst1] = bl1;
        __syncthreads();

        if (ks + 1 < NSTEP) {
            const int kb = (ks + 1) * 32;
            if constexpr (SPLIT) {
                ahc = *(const ushort4*)&ahp[kb];
                alc = *(const ushort4*)&alp[kb];
            } else {
                avc = *(const f32x4*)&ap[kb];
            }
            bh0 = *(const short8*)&bph[kb];
            bh1 = *(const short8*)&bph[kb + 8];
            bl0 = *(const short8*)&bpl[kb];
            bl1 = *(const short8*)&bpl[kb + 8];
        }

        short8 fa_h = *(const short8*)&AsH[TILE_OFF(aw) + lane * 8];
        short8 fa_l = *(const short8*)&AsL[TILE_OFF(aw) + lane * 8];
        short8 fb_h[4], fb_l[4];
#pragma unroll
        for (int j = 0; j < 4; ++j) {
            fb_h[j] = *(const short8*)&BsH[TILE_OFF(btile + j) + lane * 8];
            fb_l[j] = *(const short8*)&BsL[TILE_OFF(btile + j) + lane * 8];
        }
#pragma unroll
        for (int j = 0; j < 4; ++j) {
            acc[j] = __builtin_amdgcn_mfma_f32_16x16x32_bf16(fa_h, fb_h[j], acc[j], 0, 0, 0);
            acc[j] = __builtin_amdgcn_mfma_f32_16x16x32_bf16(fa_h, fb_l[j], acc[j], 0, 0, 0);
            acc[j] = __builtin_amdgcn_mfma_f32_16x16x32_bf16(fa_l, fb_h[j], acc[j], 0, 0, 0);
        }
    }

    // epilogue: C/D layout col=lane&15, row=quad*4+reg
#pragma unroll
    for (int r = 0; r < 4; ++r) {
        int grr = row0 + aw * 16 + quad * 4 + r;
        if (grr < N) {
#pragma unroll
            for (int j = 0; j < 4; ++j)
                C[(size_t)grr * 128 + Cc + j * 16 + m16] = acc[j][r];
        }
    }
}

// ---- propagate: gather + normalize; OUTPUT = split bf16 hi/lo -------------
__global__ __launch_bounds__(256) void propagate_kernel(
    const float* __restrict__ h, const int* __restrict__ rowptr,
    const int* __restrict__ csr_src, const float* __restrict__ dis,
    const float* __restrict__ bias, u16* __restrict__ out_hi,
    u16* __restrict__ out_lo, int N) {
    int wave = (blockIdx.x * 256 + threadIdx.x) >> 6;
    int lane = threadIdx.x & 63;
    if (wave >= N) return;
    int v = wave;
    int f = lane * 2;
    float dv = dis[v];
    float ax = 0.f, ay = 0.f;
    int beg = rowptr[v], end = rowptr[v + 1];
    int i = beg;
    for (; i + 8 <= end; i += 8) {
        int s[8];
        float ww[8];
        float2 g[8];
#pragma unroll
        for (int u = 0; u < 8; ++u) s[u] = csr_src[i + u];
#pragma unroll
        for (int u = 0; u < 8; ++u) ww[u] = dis[s[u]];
#pragma unroll
        for (int u = 0; u < 8; ++u) g[u] = *(const float2*)&h[(size_t)s[u] * 128 + f];
#pragma unroll
        for (int u = 0; u < 8; ++u) {
            float t = ww[u] * dv;
            ax += t * g[u].x;
            ay += t * g[u].y;
        }
    }
    if (i + 4 <= end) {
        int s[4];
        float ww[4];
        float2 g[4];
#pragma unroll
        for (int u = 0; u < 4; ++u) s[u] = csr_src[i + u];
#pragma unroll
        for (int u = 0; u < 4; ++u) ww[u] = dis[s[u]];
#pragma unroll
        for (int u = 0; u < 4; ++u) g[u] = *(const float2*)&h[(size_t)s[u] * 128 + f];
#pragma unroll
        for (int u = 0; u < 4; ++u) {
            float t = ww[u] * dv;
            ax += t * g[u].x;
            ay += t * g[u].y;
        }
        i += 4;
    }
    for (; i < end; ++i) {
        int s = csr_src[i];
        float ws = dis[s] * dv;
        float2 g = *(const float2*)&h[(size_t)s * 128 + f];
        ax += ws * g.x;
        ay += ws * g.y;
    }
    float2 hv = *(const float2*)&h[(size_t)v * 128 + f];
    ax += dv * dv * hv.x;
    ay += dv * dv * hv.y;
    ax += bias[f];
    ay += bias[f + 1];
    ax = fmaxf(ax, 0.f);
    ay = fmaxf(ay, 0.f);
    u16 hx, lx, hy, ly;
    split_bf16(ax, hx, lx);
    split_bf16(ay, hy, ly);
    *(ushort2*)&out_hi[(size_t)v * 128 + f] = make_ushort2(hx, hy);
    *(ushort2*)&out_lo[(size_t)v * 128 + f] = make_ushort2(lx, ly);
}

// ---- final propagate: split into z_mean / z_log_std (f32 out) -------------
__global__ __launch_bounds__(256) void propagate_final_kernel(
    const float* __restrict__ h, const int* __restrict__ rowptr,
    const int* __restrict__ csr_src, const float* __restrict__ dis,
    const float* __restrict__ bm, const float* __restrict__ bs,
    float* __restrict__ out, int N) {
    int wave = (blockIdx.x * 256 + threadIdx.x) >> 6;
    int lane = threadIdx.x & 63;
    if (wave >= N) return;
    int v = wave;
    int f = lane * 2;
    float dv = dis[v];
    float ax = 0.f, ay = 0.f;
    int beg = rowptr[v], end = rowptr[v + 1];
    int i = beg;
    for (; i + 8 <= end; i += 8) {
        int s[8];
        float ww[8];
        float2 g[8];
#pragma unroll
        for (int u = 0; u < 8; ++u) s[u] = csr_src[i + u];
#pragma unroll
        for (int u = 0; u < 8; ++u) ww[u] = dis[s[u]];
#pragma unroll
        for (int u = 0; u < 8; ++u) g[u] = *(const float2*)&h[(size_t)s[u] * 128 + f];
#pragma unroll
        for (int u = 0; u < 8; ++u) {
            float t = ww[u] * dv;
            ax += t * g[u].x;
            ay += t * g[u].y;
        }
    }
    if (i + 4 <= end) {
        int s[4];
        float ww[4];
        float2 g[4];
#pragma unroll
        for (int u = 0; u < 4; ++u) s[u] = csr_src[i + u];
#pragma unroll
        for (int u = 0; u < 4; ++u) ww[u] = dis[s[u]];
#pragma unroll
        for (int u = 0; u < 4; ++u) g[u] = *(const float2*)&h[(size_t)s[u] * 128 + f];
#pragma unroll
        for (int u = 0; u < 4; ++u) {
            float t = ww[u] * dv;
            ax += t * g[u].x;
            ay += t * g[u].y;
        }
        i += 4;
    }
    for (; i < end; ++i) {
        int s = csr_src[i];
        float ws = dis[s] * dv;
        float2 g = *(const float2*)&h[(size_t)s * 128 + f];
        ax += ws * g.x;
        ay += ws * g.y;
    }
    float2 hv = *(const float2*)&h[(size_t)v * 128 + f];
    ax += dv * dv * hv.x;
    ay += dv * dv * hv.y;
    if (f < 64) {
        *(float2*)&out[(size_t)v * 64 + f] = make_float2(ax + bm[f], ay + bm[f + 1]);
    } else {
        int g = f - 64;
        *(float2*)&out[(size_t)N * 64 + (size_t)v * 64 + g] =
            make_float2(ax + bs[g], ay + bs[g + 1]);
    }
}

extern "C" void kernel_launch(void* const* d_in, const int* in_sizes, int n_in,
                              void* d_out, int out_size, void* d_ws, size_t ws_size,
                              hipStream_t stream) {
    const float* x  = (const float*)d_in[0];
    const int*   ew = (const int*)d_in[1];
    const float* W1 = (const float*)d_in[2];
    const float* b1 = (const float*)d_in[3];
    const float* W2 = (const float*)d_in[4];
    const float* b2 = (const float*)d_in[5];
    const float* Wm = (const float*)d_in[6];
    const float* bm = (const float*)d_in[7];
    const float* Ws = (const float*)d_in[8];
    const float* bs = (const float*)d_in[9];
    float* out = (float*)d_out;

    const int IN = 512, H = 128;
    const int N = in_sizes[0] / IN;     // 50000
    const int E = in_sizes[1] / 2;      // 800000

    // ---- workspace: ~55.6 MB total (< proven-safe 58.47 MB) ----------------
    char* base = (char*)d_ws;
    size_t off = 0;
    auto alloc = [&](size_t bytes) -> char* {
        char* p = base + off;
        off = (off + bytes + 255) & ~(size_t)255;
        return p;
    };
    char*  degcur  = (char*) alloc(400384);             // deg + cursor (zeroed)
    float* dis     = (float*)alloc((size_t)N * 4);
    int*   rowptr  = (int*)  alloc((size_t)(N + 1) * 4);
    int*   aux     = (int*)  alloc(256 * 4);
    int*   csr_src = (int*)  alloc((size_t)E * 4);
    u16*   W1t_hi  = (u16*)  alloc((size_t)IN * H * 2);
    u16*   W1t_lo  = (u16*)  alloc((size_t)IN * H * 2);
    u16*   W2t_hi  = (u16*)  alloc((size_t)H * H * 2);
    u16*   W2t_lo  = (u16*)  alloc((size_t)H * H * 2);
    u16*   Wct_hi  = (u16*)  alloc((size_t)H * H * 2);
    u16*   Wct_lo  = (u16*)  alloc((size_t)H * H * 2);
    float* hA      = (float*)alloc((size_t)N * H * 4);  // GEMM outputs (f32)
    u16*   hBhi    = (u16*)  alloc((size_t)N * H * 2);  // propagate out hi
    u16*   hBlo    = (u16*)  alloc((size_t)N * H * 2);  // propagate out lo
    (void)ws_size; (void)n_in; (void)out_size;

    int* deg    = (int*)degcur;
    int* cursor = (int*)(degcur + 200192);

    hipMemsetAsync(degcur, 0, 400384, stream);

    const int eblocks = (E + 255) / 256;
    const int nblocks = (N + 255) / 256;

    conv_deg_kernel<<<CONVB + eblocks, 256, 0, stream>>>(
        W1, W2, Wm, Ws, W1t_hi, W1t_lo, W2t_hi, W2t_lo, Wct_hi, Wct_lo,
        ew, deg, E);
    scan_block_kernel<<<nblocks, 256, 0, stream>>>(deg, rowptr, aux, dis, N);
    scan_aux_kernel<<<1, 256, 0, stream>>>(aux, nblocks);
    add_offsets_kernel<<<nblocks, 256, 0, stream>>>(rowptr, aux, N, E);
    fill_csr_kernel<<<eblocks, 256, 0, stream>>>(ew, rowptr, cursor, csr_src, E);

    const int gblocks = (N + 31) / 32;   // 1563
    const int pblocks = (N * 64 + 255) / 256;

    gemm_tiled<512, false><<<gblocks, 256, 0, stream>>>(
        x, nullptr, nullptr, W1t_hi, W1t_lo, hA, N);
    propagate_kernel<<<pblocks, 256, 0, stream>>>(hA, rowptr, csr_src, dis,
                                                  b1, hBhi, hBlo, N);
    gemm_tiled<128, true><<<gblocks, 256, 0, stream>>>(
        nullptr, hBhi, hBlo, W2t_hi, W2t_lo, hA, N);
    propagate_kernel<<<pblocks, 256, 0, stream>>>(hA, rowptr, csr_src, dis,
                                                  b2, hBhi, hBlo, N);
    gemm_tiled<128, true><<<gblocks, 256, 0, stream>>>(
        nullptr, hBhi, hBlo, Wct_hi, Wct_lo, hA, N);
    propagate_final_kernel<<<pblocks, 256, 0, stream>>>(hA, rowptr, csr_src, dis,
                                                        bm, bs, out, N);
}